// Round 4
// baseline (397.321 us; speedup 1.0000x reference)
//
#include <hip/hip_runtime.h>
#include <hip/hip_bf16.h>

#define TT 4096      // tokens (B*S)
#define DD 768       // model dim
#define FF 3072      // ffn dim
#define EE 8         // experts
#define NSLOT 8192   // 2*TT (top-2)
#define NSLOT_PAD 8320

// s_waitcnt imm encodings (gfx9): vmcnt[3:0]|expcnt<<4|lgkmcnt<<8|vmcnt[5:4]<<14
#define WAITCNT_VM4 0x0F74   // vmcnt(4), expcnt/lgkmcnt no-wait
#define WAITCNT_VM3 0x0F73   // vmcnt(3)

typedef __attribute__((ext_vector_type(8))) short bf16x8;
typedef __attribute__((ext_vector_type(4))) float f32x4;
typedef const __attribute__((address_space(1))) void* gas1_t;
typedef __attribute__((address_space(3))) void* las3_t;

// ---------------- router2: 256 blocks x 16 tokens; rw in LDS; no global atomics ----
__global__ __launch_bounds__(256) void router2_kernel(const float* __restrict__ x,
    const float* __restrict__ rw, int* __restrict__ tokE, float* __restrict__ tokW,
    int* __restrict__ blkCnt) {
  __shared__ float rws[EE * 832];
  __shared__ int cnt_s[EE];
  int tid = threadIdx.x;
  if (tid < EE) cnt_s[tid] = 0;
#pragma unroll
  for (int k = 0; k < 6; ++k) {
    int c = tid + k * 256;            // 0..1535
    int e = c / 192, rem = c % 192;
    int s = rem / 12, i = rem % 12;
    float4 v = *(const float4*)&rw[e * DD + s * 48 + i * 4];
    *(float4*)&rws[e * 832 + s * 52 + i * 4] = v;
  }
  __syncthreads();
  int lane = tid & 63;
  int sl = lane & 15;                  // d-slice
  int t = blockIdx.x * 16 + (tid >> 6) * 4 + (lane >> 4);
  const float4* xp = (const float4*)(x + (size_t)t * DD + sl * 48);
  float acc[EE];
#pragma unroll
  for (int e = 0; e < EE; ++e) acc[e] = 0.f;
#pragma unroll
  for (int i = 0; i < 12; ++i) {
    float4 xv = xp[i];
#pragma unroll
    for (int e = 0; e < EE; ++e) {
      float4 rv = *(const float4*)&rws[e * 832 + sl * 52 + i * 4];
      acc[e] = fmaf(xv.x, rv.x, fmaf(xv.y, rv.y, fmaf(xv.z, rv.z, fmaf(xv.w, rv.w, acc[e]))));
    }
  }
#pragma unroll
  for (int off = 8; off > 0; off >>= 1) {
#pragma unroll
    for (int e = 0; e < EE; ++e) acc[e] += __shfl_xor(acc[e], off);
  }
  if (sl == 0) {
    float v0 = -1e30f; int e0 = 0;
#pragma unroll
    for (int e = 0; e < EE; ++e) { if (acc[e] > v0) { v0 = acc[e]; e0 = e; } }
    float v1 = -1e30f; int e1 = 0;
#pragma unroll
    for (int e = 0; e < EE; ++e) { if (e != e0 && acc[e] > v1) { v1 = acc[e]; e1 = e; } }
    float w1 = 1.f / (1.f + __expf(v0 - v1));
    float w0 = 1.f - w1;
    tokE[2 * t] = e0; tokE[2 * t + 1] = e1;
    tokW[2 * t] = w0; tokW[2 * t + 1] = w1;
    atomicAdd(&cnt_s[e0], 1);
    atomicAdd(&cnt_s[e1], 1);
  }
  __syncthreads();
  if (tid < EE) blkCnt[blockIdx.x * EE + tid] = cnt_s[tid];
}

// ---------------- offsets2: 256-wide scan of blkCnt; offsets, bases, tile tables ---
__global__ __launch_bounds__(256) void offsets2_kernel(const int* __restrict__ blkCnt,
    int* __restrict__ offs, int* __restrict__ blkBase,
    int* __restrict__ tile1, int* __restrict__ tile2, int* __restrict__ meta) {
  __shared__ int wsum[4][EE];
  int tid = threadIdx.x;
  int lane = tid & 63, w = tid >> 6;
  int c[EE], s[EE];
#pragma unroll
  for (int e = 0; e < EE; ++e) { c[e] = blkCnt[tid * EE + e]; s[e] = c[e]; }
#pragma unroll
  for (int off = 1; off < 64; off <<= 1) {
#pragma unroll
    for (int e = 0; e < EE; ++e) {
      int v = __shfl_up(s[e], off);
      if (lane >= off) s[e] += v;
    }
  }
  if (lane == 63) {
#pragma unroll
    for (int e = 0; e < EE; ++e) wsum[w][e] = s[e];
  }
  __syncthreads();
#pragma unroll
  for (int e = 0; e < EE; ++e) {
    int pre = 0;
    for (int w2 = 0; w2 < w; ++w2) pre += wsum[w2][e];
    s[e] += pre;
  }
  int tot[EE];
#pragma unroll
  for (int e = 0; e < EE; ++e) tot[e] = wsum[0][e] + wsum[1][e] + wsum[2][e] + wsum[3][e];
  int offl[EE + 1];
  offl[0] = 0;
#pragma unroll
  for (int e = 0; e < EE; ++e) offl[e + 1] = offl[e] + tot[e];
#pragma unroll
  for (int e = 0; e < EE; ++e) blkBase[tid * EE + e] = offl[e] + s[e] - c[e];
  if (tid == 0) {
    for (int e = 0; e <= EE; ++e) offs[e] = offl[e];
    int n1 = 0, n2 = 0;
    for (int e = 0; e < EE; ++e) { n1 += (tot[e] + 127) / 128; n2 += (tot[e] + 63) / 64; }
    meta[0] = n1; meta[1] = n2;
  }
  if (tid < EE) {
    int p1 = 0, p2 = 0;
    for (int e = 0; e < tid; ++e) { p1 += (tot[e] + 127) / 128; p2 += (tot[e] + 63) / 64; }
    for (int m = 0; m < tot[tid]; m += 128) tile1[p1++] = (tid << 20) | m;
    for (int m = 0; m < tot[tid]; m += 64)  tile2[p2++] = (tid << 20) | m;
  }
}

// ---------------- scatter_gather2: 256 blocks x 16 tokens; LDS cursors ------------
__global__ __launch_bounds__(256) void scatter_gather2_kernel(const float* __restrict__ x,
    const int* __restrict__ tokE, const float* __restrict__ tokW,
    const int* __restrict__ blkBase, int* __restrict__ slotIdx, float* __restrict__ slotW,
    __hip_bfloat16* __restrict__ Xg) {
  __shared__ int base_s[EE], lcur[EE];
  __shared__ int sl_s[16][2];
  int tid = threadIdx.x;
  int b = blockIdx.x;
  if (tid < EE) { base_s[tid] = blkBase[b * EE + tid]; lcur[tid] = 0; }
  __syncthreads();
  if (tid < 16) {
    int t = b * 16 + tid;
    int e0 = tokE[2 * t], e1 = tokE[2 * t + 1];
    int s0 = base_s[e0] + atomicAdd(&lcur[e0], 1);
    int s1 = base_s[e1] + atomicAdd(&lcur[e1], 1);
    slotIdx[2 * t] = s0; slotIdx[2 * t + 1] = s1;
    slotW[s0] = tokW[2 * t]; slotW[s1] = tokW[2 * t + 1];
    sl_s[tid][0] = s0; sl_s[tid][1] = s1;
  }
  __syncthreads();
  int k = tid >> 4, p = tid & 15;
  int t = b * 16 + k;
  int s0 = sl_s[k][0], s1 = sl_s[k][1];
  const float4* src = (const float4*)(x + (size_t)t * DD + p * 48);
  ushort4* d0 = (ushort4*)(Xg + (size_t)s0 * DD + p * 48);
  ushort4* d1 = (ushort4*)(Xg + (size_t)s1 * DD + p * 48);
#pragma unroll
  for (int i = 0; i < 12; ++i) {
    float4 v = src[i];
    union { ushort4 u; __hip_bfloat16 h[4]; } cv;
    cv.h[0] = __float2bfloat16(v.x);
    cv.h[1] = __float2bfloat16(v.y);
    cv.h[2] = __float2bfloat16(v.z);
    cv.h[3] = __float2bfloat16(v.w);
    d0[i] = cv.u;
    d1[i] = cv.u;
  }
}

// fused transpose-convert for both weight tensors: [K][N] fp32 -> [N][K] bf16
__global__ void transpose_convert_kernel(const float* __restrict__ w_fc, __hip_bfloat16* __restrict__ wfcT,
                                         const float* __restrict__ w_proj, __hip_bfloat16* __restrict__ wprojT) {
  __shared__ float tile[64][65];
  int bx = blockIdx.x;
  const float* S; __hip_bfloat16* D; int K, N, n0, k0;
  if (bx < 576) { S = w_fc;   D = wfcT;   K = DD; N = FF; n0 = (bx % 48) * 64; k0 = (bx / 48) * 64; }
  else { bx -= 576; S = w_proj; D = wprojT; K = FF; N = DD; n0 = (bx % 12) * 64; k0 = (bx / 12) * 64; }
  S += (size_t)blockIdx.z * K * N;
  D += (size_t)blockIdx.z * K * N;
  int tid = threadIdx.x;
#pragma unroll
  for (int i = 0; i < 4; ++i) {
    int slot = i * 256 + tid;
    int r = slot >> 4, c4 = slot & 15;
    float4 v = *(const float4*)&S[(size_t)(k0 + r) * N + n0 + c4 * 4];
    tile[r][c4 * 4 + 0] = v.x; tile[r][c4 * 4 + 1] = v.y;
    tile[r][c4 * 4 + 2] = v.z; tile[r][c4 * 4 + 3] = v.w;
  }
  __syncthreads();
#pragma unroll
  for (int i = 0; i < 4; ++i) {
    int slot = i * 256 + tid;
    int n = slot >> 4, kc = slot & 15;
    union { ushort4 u; __hip_bfloat16 h[4]; } cv;
    cv.h[0] = __float2bfloat16(tile[kc * 4 + 0][n]);
    cv.h[1] = __float2bfloat16(tile[kc * 4 + 1][n]);
    cv.h[2] = __float2bfloat16(tile[kc * 4 + 2][n]);
    cv.h[3] = __float2bfloat16(tile[kc * 4 + 3][n]);
    *(ushort4*)&D[(size_t)(n0 + n) * K + k0 + kc * 4] = cv.u;
  }
}

// fast exact-gelu via A&S 7.1.26 erf (max abs err 1.5e-7)
__device__ __forceinline__ float gelu_f(float v) {
  float z = v * 0.70710678118654752f;
  float az = fabsf(z);
  float t = 1.0f / (1.0f + 0.3275911f * az);
  float poly = t * (0.254829592f + t * (-0.284496736f + t * (1.421413741f +
               t * (-1.453152027f + t * 1.061405429f))));
  float erf_abs = 1.0f - poly * __expf(-az * az);
  float erf = copysignf(erf_abs, z);
  return 0.5f * v * (1.0f + erf);
}

// chunk swizzle for BK=32 rows (4 x 16B chunks/row): keeps ds_read_b128 at 2-way (free)
__device__ __forceinline__ int swz4(int m) { return (m + (m >> 2)) & 3; }

// GEMM1: H = gelu(Xg @ wfcT + b_fc); 128x128 tile, BK=32, 2-buf pipelined K-loop.
// Raw s_barrier + vmcnt(4): next tile's global_load_lds stay in flight across compute.
__global__ __launch_bounds__(256) void gemm1_kernel(const __hip_bfloat16* __restrict__ Xg,
    const __hip_bfloat16* __restrict__ wfcT, const float* __restrict__ b_fc,
    __hip_bfloat16* __restrict__ H, const int* __restrict__ offs,
    const int* __restrict__ tile1, const int* __restrict__ meta) {
  __shared__ __align__(16) short As[2][128 * 32];
  __shared__ __align__(16) short Bs[2][128 * 32];
  if ((int)blockIdx.y >= meta[0]) return;
  int tv = tile1[blockIdx.y];
  int e = tv >> 20;
  int m_base = tv & 0xFFFFF;
  int off_e = offs[e];
  int n_e = offs[e + 1] - off_e;
  int n0 = blockIdx.x * 128;
  const short* A = (const short*)Xg + (size_t)(off_e + m_base) * DD;
  const short* B = (const short*)wfcT + (size_t)e * FF * DD + (size_t)n0 * DD;
  int tid = threadIdx.x;
  int lane = tid & 63, wid = tid >> 6;
  int l15 = lane & 15, q = lane >> 4;
  int wm = wid & 1, wn = wid >> 1;
  // staging: LDS slot fs holds global chunk c = (fs&3) ^ swz4(row)
  int fs0 = tid, fs1 = tid + 256;
  int m0 = fs0 >> 2, c0 = (fs0 & 3) ^ swz4(m0);
  int m1 = fs1 >> 2, c1 = (fs1 & 3) ^ swz4(m1);
  const short* gA0 = A + (size_t)m0 * DD + c0 * 8;
  const short* gA1 = A + (size_t)m1 * DD + c1 * 8;
  const short* gB0 = B + (size_t)m0 * DD + c0 * 8;
  const short* gB1 = B + (size_t)m1 * DD + c1 * 8;
  // fragment LDS offsets (shorts)
  int aoff[4], boff[4];
#pragma unroll
  for (int mi = 0; mi < 4; ++mi) {
    int r = wm * 64 + mi * 16 + l15;
    aoff[mi] = (r * 4 + (q ^ swz4(r))) * 8;
  }
#pragma unroll
  for (int ni = 0; ni < 4; ++ni) {
    int r = wn * 64 + ni * 16 + l15;
    boff[ni] = (r * 4 + (q ^ swz4(r))) * 8;
  }
  f32x4 acc[4][4] = {};
  // prologue: stage tile 0 -> buffer 0
  __builtin_amdgcn_global_load_lds((gas1_t)gA0, (las3_t)(&As[0][0] + fs0 * 8), 16, 0, 0);
  __builtin_amdgcn_global_load_lds((gas1_t)gA1, (las3_t)(&As[0][0] + fs1 * 8), 16, 0, 0);
  __builtin_amdgcn_global_load_lds((gas1_t)gB0, (las3_t)(&Bs[0][0] + fs0 * 8), 16, 0, 0);
  __builtin_amdgcn_global_load_lds((gas1_t)gB1, (las3_t)(&Bs[0][0] + fs1 * 8), 16, 0, 0);
  gA0 += 32; gA1 += 32; gB0 += 32; gB1 += 32;
  for (int it = 0; it < DD / 32; ++it) {
    int cur = it & 1, nxt = cur ^ 1;
    short* curA = &As[cur][0];
    short* curB = &Bs[cur][0];
    __builtin_amdgcn_s_barrier();   // all waves finished reading buf[nxt] -> safe to overwrite
    __builtin_amdgcn_global_load_lds((gas1_t)gA0, (las3_t)(&As[nxt][0] + fs0 * 8), 16, 0, 0);
    __builtin_amdgcn_global_load_lds((gas1_t)gA1, (las3_t)(&As[nxt][0] + fs1 * 8), 16, 0, 0);
    __builtin_amdgcn_global_load_lds((gas1_t)gB0, (las3_t)(&Bs[nxt][0] + fs0 * 8), 16, 0, 0);
    __builtin_amdgcn_global_load_lds((gas1_t)gB1, (las3_t)(&Bs[nxt][0] + fs1 * 8), 16, 0, 0);
    gA0 += 32; gA1 += 32; gB0 += 32; gB1 += 32;
    __builtin_amdgcn_s_waitcnt(WAITCNT_VM4);  // own cur-tile loads done (4 newest in flight)
    __builtin_amdgcn_s_barrier();             // => ALL waves' cur-tile loads done
    bf16x8 af[4], bfr[4];
#pragma unroll
    for (int mi = 0; mi < 4; ++mi) af[mi] = *(const bf16x8*)(curA + aoff[mi]);
#pragma unroll
    for (int ni = 0; ni < 4; ++ni) bfr[ni] = *(const bf16x8*)(curB + boff[ni]);
#pragma unroll
    for (int mi = 0; mi < 4; ++mi)
#pragma unroll
      for (int ni = 0; ni < 4; ++ni)
        acc[mi][ni] = __builtin_amdgcn_mfma_f32_16x16x32_bf16(af[mi], bfr[ni], acc[mi][ni], 0, 0, 0);
  }
  float bias[4];
#pragma unroll
  for (int ni = 0; ni < 4; ++ni) bias[ni] = b_fc[e * FF + n0 + wn * 64 + ni * 16 + l15];
  __hip_bfloat16* Hp = H + (size_t)(off_e + m_base) * FF + n0;
#pragma unroll
  for (int mi = 0; mi < 4; ++mi) {
#pragma unroll
    for (int r = 0; r < 4; ++r) {
      int ml = wm * 64 + mi * 16 + q * 4 + r;
      if (m_base + ml < n_e) {
#pragma unroll
        for (int ni = 0; ni < 4; ++ni) {
          int nl = wn * 64 + ni * 16 + l15;
          float v = acc[mi][ni][r] + bias[ni];
          Hp[(size_t)ml * FF + nl] = __float2bfloat16(gelu_f(v));
        }
      }
    }
  }
}

// GEMM2: Yw = w(slot) * (H @ wprojT + b_proj); 64x128 tile, BK=32, same pipeline
__global__ __launch_bounds__(256) void gemm2_kernel(const __hip_bfloat16* __restrict__ H,
    const __hip_bfloat16* __restrict__ wprojT, const float* __restrict__ b_proj,
    const float* __restrict__ slotW, float* __restrict__ Yw, const int* __restrict__ offs,
    const int* __restrict__ tile2, const int* __restrict__ meta) {
  __shared__ __align__(16) short As[2][64 * 32];
  __shared__ __align__(16) short Bs[2][128 * 32];
  if ((int)blockIdx.y >= meta[1]) return;
  int tv = tile2[blockIdx.y];
  int e = tv >> 20;
  int m_base = tv & 0xFFFFF;
  int off_e = offs[e];
  int n_e = offs[e + 1] - off_e;
  int n0 = blockIdx.x * 128;
  const short* A = (const short*)H + (size_t)(off_e + m_base) * FF;
  const short* B = (const short*)wprojT + (size_t)e * DD * FF + (size_t)n0 * FF;
  int tid = threadIdx.x;
  int lane = tid & 63, wid = tid >> 6;
  int l15 = lane & 15, q = lane >> 4;
  int wm = wid & 1, wn = wid >> 1;
  int fs0 = tid, fs1 = tid + 256;
  int m0 = fs0 >> 2, c0 = (fs0 & 3) ^ swz4(m0);   // A rows 0..63 (fs0 only)
  int m1 = fs1 >> 2, c1 = (fs1 & 3) ^ swz4(m1);   // B rows 64..127
  const short* gA0 = A + (size_t)m0 * FF + c0 * 8;
  const short* gB0 = B + (size_t)m0 * FF + c0 * 8;
  const short* gB1 = B + (size_t)m1 * FF + c1 * 8;
  int aoff[2], boff[4];
#pragma unroll
  for (int mi = 0; mi < 2; ++mi) {
    int r = wm * 32 + mi * 16 + l15;
    aoff[mi] = (r * 4 + (q ^ swz4(r))) * 8;
  }
#pragma unroll
  for (int ni = 0; ni < 4; ++ni) {
    int r = wn * 64 + ni * 16 + l15;
    boff[ni] = (r * 4 + (q ^ swz4(r))) * 8;
  }
  f32x4 acc[2][4] = {};
  __builtin_amdgcn_global_load_lds((gas1_t)gA0, (las3_t)(&As[0][0] + fs0 * 8), 16, 0, 0);
  __builtin_amdgcn_global_load_lds((gas1_t)gB0, (las3_t)(&Bs[0][0] + fs0 * 8), 16, 0, 0);
  __builtin_amdgcn_global_load_lds((gas1_t)gB1, (las3_t)(&Bs[0][0] + fs1 * 8), 16, 0, 0);
  gA0 += 32; gB0 += 32; gB1 += 32;
  for (int it = 0; it < FF / 32; ++it) {
    int cur = it & 1, nxt = cur ^ 1;
    short* curA = &As[cur][0];
    short* curB = &Bs[cur][0];
    __builtin_amdgcn_s_barrier();
    __builtin_amdgcn_global_load_lds((gas1_t)gA0, (las3_t)(&As[nxt][0] + fs0 * 8), 16, 0, 0);
    __builtin_amdgcn_global_load_lds((gas1_t)gB0, (las3_t)(&Bs[nxt][0] + fs0 * 8), 16, 0, 0);
    __builtin_amdgcn_global_load_lds((gas1_t)gB1, (las3_t)(&Bs[nxt][0] + fs1 * 8), 16, 0, 0);
    gA0 += 32; gB0 += 32; gB1 += 32;
    __builtin_amdgcn_s_waitcnt(WAITCNT_VM3);
    __builtin_amdgcn_s_barrier();
    bf16x8 af[2], bfr[4];
#pragma unroll
    for (int mi = 0; mi < 2; ++mi) af[mi] = *(const bf16x8*)(curA + aoff[mi]);
#pragma unroll
    for (int ni = 0; ni < 4; ++ni) bfr[ni] = *(const bf16x8*)(curB + boff[ni]);
#pragma unroll
    for (int mi = 0; mi < 2; ++mi)
#pragma unroll
      for (int ni = 0; ni < 4; ++ni)
        acc[mi][ni] = __builtin_amdgcn_mfma_f32_16x16x32_bf16(af[mi], bfr[ni], acc[mi][ni], 0, 0, 0);
  }
  float bias[4];
#pragma unroll
  for (int ni = 0; ni < 4; ++ni) bias[ni] = b_proj[e * DD + n0 + wn * 64 + ni * 16 + l15];
  float* Yp = Yw + (size_t)(off_e + m_base) * DD + n0;
#pragma unroll
  for (int mi = 0; mi < 2; ++mi) {
#pragma unroll
    for (int r = 0; r < 4; ++r) {
      int ml = wm * 32 + mi * 16 + q * 4 + r;
      if (m_base + ml < n_e) {
        float w = slotW[off_e + m_base + ml];
#pragma unroll
        for (int ni = 0; ni < 4; ++ni) {
          int nl = wn * 64 + ni * 16 + l15;
          Yp[(size_t)ml * DD + nl] = w * (acc[mi][ni][r] + bias[ni]);
        }
      }
    }
  }
}

// out[t] = Yw[slot0(t)] + Yw[slot1(t)]  (already gate-weighted)
__global__ void combine_kernel(const float* __restrict__ Yw, const int* __restrict__ slotIdx,
                               float* __restrict__ out) {
  int idx = blockIdx.x * 256 + threadIdx.x;
  int t = idx / (DD / 4);
  int g = idx - t * (DD / 4);
  int s0 = slotIdx[2 * t], s1 = slotIdx[2 * t + 1];
  const float4 a = ((const float4*)(Yw + (size_t)s0 * DD))[g];
  const float4 b = ((const float4*)(Yw + (size_t)s1 * DD))[g];
  float4 o;
  o.x = a.x + b.x; o.y = a.y + b.y; o.z = a.z + b.z; o.w = a.w + b.w;
  ((float4*)(out + (size_t)t * DD))[g] = o;
}

extern "C" void kernel_launch(void* const* d_in, const int* in_sizes, int n_in,
                              void* d_out, int out_size, void* d_ws, size_t ws_size,
                              hipStream_t stream) {
  const float* x        = (const float*)d_in[0];
  const float* router_w = (const float*)d_in[1];
  const float* w_fc     = (const float*)d_in[2];
  const float* b_fc     = (const float*)d_in[3];
  const float* w_proj   = (const float*)d_in[4];
  const float* b_proj   = (const float*)d_in[5];
  float* out = (float*)d_out;

  char* p = (char*)d_ws;
  auto alloc = [&](size_t bytes) {
    char* r = p;
    p += (bytes + 255) & ~(size_t)255;
    return r;
  };
  __hip_bfloat16* wfcT   = (__hip_bfloat16*)alloc((size_t)EE * FF * DD * 2);  // [E][F][D]
  __hip_bfloat16* wprojT = (__hip_bfloat16*)alloc((size_t)EE * DD * FF * 2);  // [E][D][F]
  __hip_bfloat16* Xg     = (__hip_bfloat16*)alloc((size_t)NSLOT_PAD * DD * 2);
  __hip_bfloat16* H      = (__hip_bfloat16*)alloc((size_t)NSLOT_PAD * FF * 2);
  float*          Yw     = (float*)alloc((size_t)NSLOT_PAD * DD * 4);
  int*   tokE    = (int*)alloc(TT * 2 * 4);
  float* tokW    = (float*)alloc(TT * 2 * 4);
  int*   slotIdx = (int*)alloc(TT * 2 * 4);
  float* slotW   = (float*)alloc(NSLOT_PAD * 4);
  int*   blkCnt  = (int*)alloc(256 * EE * 4);
  int*   blkBase = (int*)alloc(256 * EE * 4);
  int*   tile1   = (int*)alloc(128 * 4);
  int*   tile2   = (int*)alloc(256 * 4);
  int*   offs    = (int*)alloc(64);
  int*   meta    = (int*)alloc(64);

  router2_kernel<<<256, 256, 0, stream>>>(x, router_w, tokE, tokW, blkCnt);
  offsets2_kernel<<<1, 256, 0, stream>>>(blkCnt, offs, blkBase, tile1, tile2, meta);
  scatter_gather2_kernel<<<256, 256, 0, stream>>>(x, tokE, tokW, blkBase, slotIdx, slotW, Xg);
  transpose_convert_kernel<<<dim3(1152, 1, EE), 256, 0, stream>>>(w_fc, wfcT, w_proj, wprojT);
  gemm1_kernel<<<dim3(FF / 128, 72), 256, 0, stream>>>(Xg, wfcT, b_fc, H, offs, tile1, meta);
  gemm2_kernel<<<dim3(DD / 128, 136), 256, 0, stream>>>(H, wprojT, b_proj, slotW, Yw, offs, tile2, meta);
  combine_kernel<<<TT * (DD / 4) / 256, 256, 0, stream>>>(Yw, slotIdx, out);
}

// Round 5
// 390.914 us; speedup vs baseline: 1.0164x; 1.0164x over previous
//
#include <hip/hip_runtime.h>
#include <hip/hip_bf16.h>

#define TT 4096      // tokens (B*S)
#define DD 768       // model dim
#define FF 3072      // ffn dim
#define EE 8         // experts
#define NSLOT 8192   // 2*TT (top-2)
#define NSLOT_PAD 8320

// s_waitcnt imm encodings (gfx9): vmcnt[3:0]|expcnt<<4|lgkmcnt<<8|vmcnt[5:4]<<14
#define WAITCNT_VM4 0x0F74   // vmcnt(4)
#define WAITCNT_VM7 0x0F77   // vmcnt(7)

typedef __attribute__((ext_vector_type(8))) short bf16x8;
typedef __attribute__((ext_vector_type(4))) float f32x4;
typedef const __attribute__((address_space(1))) void* gas1_t;
typedef __attribute__((address_space(3))) void* las3_t;

// ---------------- router2: 256 blocks x 16 tokens; rw in LDS; no global atomics ----
__global__ __launch_bounds__(256) void router2_kernel(const float* __restrict__ x,
    const float* __restrict__ rw, int* __restrict__ tokE, float* __restrict__ tokW,
    int* __restrict__ blkCnt) {
  __shared__ float rws[EE * 832];
  __shared__ int cnt_s[EE];
  int tid = threadIdx.x;
  if (tid < EE) cnt_s[tid] = 0;
#pragma unroll
  for (int k = 0; k < 6; ++k) {
    int c = tid + k * 256;            // 0..1535
    int e = c / 192, rem = c % 192;
    int s = rem / 12, i = rem % 12;
    float4 v = *(const float4*)&rw[e * DD + s * 48 + i * 4];
    *(float4*)&rws[e * 832 + s * 52 + i * 4] = v;
  }
  __syncthreads();
  int lane = tid & 63;
  int sl = lane & 15;                  // d-slice
  int t = blockIdx.x * 16 + (tid >> 6) * 4 + (lane >> 4);
  const float4* xp = (const float4*)(x + (size_t)t * DD + sl * 48);
  float acc[EE];
#pragma unroll
  for (int e = 0; e < EE; ++e) acc[e] = 0.f;
#pragma unroll
  for (int i = 0; i < 12; ++i) {
    float4 xv = xp[i];
#pragma unroll
    for (int e = 0; e < EE; ++e) {
      float4 rv = *(const float4*)&rws[e * 832 + sl * 52 + i * 4];
      acc[e] = fmaf(xv.x, rv.x, fmaf(xv.y, rv.y, fmaf(xv.z, rv.z, fmaf(xv.w, rv.w, acc[e]))));
    }
  }
#pragma unroll
  for (int off = 8; off > 0; off >>= 1) {
#pragma unroll
    for (int e = 0; e < EE; ++e) acc[e] += __shfl_xor(acc[e], off);
  }
  if (sl == 0) {
    float v0 = -1e30f; int e0 = 0;
#pragma unroll
    for (int e = 0; e < EE; ++e) { if (acc[e] > v0) { v0 = acc[e]; e0 = e; } }
    float v1 = -1e30f; int e1 = 0;
#pragma unroll
    for (int e = 0; e < EE; ++e) { if (e != e0 && acc[e] > v1) { v1 = acc[e]; e1 = e; } }
    float w1 = 1.f / (1.f + __expf(v0 - v1));
    float w0 = 1.f - w1;
    tokE[2 * t] = e0; tokE[2 * t + 1] = e1;
    tokW[2 * t] = w0; tokW[2 * t + 1] = w1;
    atomicAdd(&cnt_s[e0], 1);
    atomicAdd(&cnt_s[e1], 1);
  }
  __syncthreads();
  if (tid < EE) blkCnt[blockIdx.x * EE + tid] = cnt_s[tid];
}

// ---------------- offsets2: 256-wide scan of blkCnt; offsets, bases, tile tables ---
__global__ __launch_bounds__(256) void offsets2_kernel(const int* __restrict__ blkCnt,
    int* __restrict__ offs, int* __restrict__ blkBase,
    int* __restrict__ tile1, int* __restrict__ tile2, int* __restrict__ meta) {
  __shared__ int wsum[4][EE];
  int tid = threadIdx.x;
  int lane = tid & 63, w = tid >> 6;
  int c[EE], s[EE];
#pragma unroll
  for (int e = 0; e < EE; ++e) { c[e] = blkCnt[tid * EE + e]; s[e] = c[e]; }
#pragma unroll
  for (int off = 1; off < 64; off <<= 1) {
#pragma unroll
    for (int e = 0; e < EE; ++e) {
      int v = __shfl_up(s[e], off);
      if (lane >= off) s[e] += v;
    }
  }
  if (lane == 63) {
#pragma unroll
    for (int e = 0; e < EE; ++e) wsum[w][e] = s[e];
  }
  __syncthreads();
#pragma unroll
  for (int e = 0; e < EE; ++e) {
    int pre = 0;
    for (int w2 = 0; w2 < w; ++w2) pre += wsum[w2][e];
    s[e] += pre;
  }
  int tot[EE];
#pragma unroll
  for (int e = 0; e < EE; ++e) tot[e] = wsum[0][e] + wsum[1][e] + wsum[2][e] + wsum[3][e];
  int offl[EE + 1];
  offl[0] = 0;
#pragma unroll
  for (int e = 0; e < EE; ++e) offl[e + 1] = offl[e] + tot[e];
#pragma unroll
  for (int e = 0; e < EE; ++e) blkBase[tid * EE + e] = offl[e] + s[e] - c[e];
  if (tid == 0) {
    for (int e = 0; e <= EE; ++e) offs[e] = offl[e];
    int n1 = 0, n2 = 0;
    for (int e = 0; e < EE; ++e) { n1 += (tot[e] + 127) / 128; n2 += (tot[e] + 63) / 64; }
    meta[0] = n1; meta[1] = n2;
  }
  if (tid < EE) {
    int p1 = 0, p2 = 0;
    for (int e = 0; e < tid; ++e) { p1 += (tot[e] + 127) / 128; p2 += (tot[e] + 63) / 64; }
    for (int m = 0; m < tot[tid]; m += 128) tile1[p1++] = (tid << 20) | m;
    for (int m = 0; m < tot[tid]; m += 64)  tile2[p2++] = (tid << 20) | m;
  }
}

// ---------------- scatter_gather2: coalesced copy to both slots; records slot->tok --
__global__ __launch_bounds__(256) void scatter_gather2_kernel(const float* __restrict__ x,
    const int* __restrict__ tokE, const float* __restrict__ tokW,
    const int* __restrict__ blkBase, int* __restrict__ slotIdx, float* __restrict__ slotW,
    int* __restrict__ slotTok, __hip_bfloat16* __restrict__ Xg) {
  __shared__ int base_s[EE], lcur[EE];
  __shared__ int sl_s[16][2];
  int tid = threadIdx.x;
  int b = blockIdx.x;
  if (tid < EE) { base_s[tid] = blkBase[b * EE + tid]; lcur[tid] = 0; }
  __syncthreads();
  if (tid < 16) {
    int t = b * 16 + tid;
    int e0 = tokE[2 * t], e1 = tokE[2 * t + 1];
    int s0 = base_s[e0] + atomicAdd(&lcur[e0], 1);
    int s1 = base_s[e1] + atomicAdd(&lcur[e1], 1);
    slotIdx[2 * t] = s0; slotIdx[2 * t + 1] = s1;
    slotW[s0] = tokW[2 * t]; slotW[s1] = tokW[2 * t + 1];
    slotTok[s0] = t; slotTok[s1] = t;
    sl_s[tid][0] = s0; sl_s[tid][1] = s1;
  }
  __syncthreads();
  int k = tid >> 4, p = tid & 15;
  int t = b * 16 + k;
  int s0 = sl_s[k][0], s1 = sl_s[k][1];
  const float4* src = (const float4*)(x + (size_t)t * DD);
  ushort4* d0 = (ushort4*)(Xg + (size_t)s0 * DD);
  ushort4* d1 = (ushort4*)(Xg + (size_t)s1 * DD);
#pragma unroll
  for (int i = 0; i < 12; ++i) {
    int idx = i * 16 + p;               // lanes contiguous -> coalesced 256B/128B
    float4 v = src[idx];
    union { ushort4 u; __hip_bfloat16 h[4]; } cv;
    cv.h[0] = __float2bfloat16(v.x);
    cv.h[1] = __float2bfloat16(v.y);
    cv.h[2] = __float2bfloat16(v.z);
    cv.h[3] = __float2bfloat16(v.w);
    d0[idx] = cv.u;
    d1[idx] = cv.u;
  }
}

// fused transpose-convert for both weight tensors: [K][N] fp32 -> [N][K] bf16
__global__ void transpose_convert_kernel(const float* __restrict__ w_fc, __hip_bfloat16* __restrict__ wfcT,
                                         const float* __restrict__ w_proj, __hip_bfloat16* __restrict__ wprojT) {
  __shared__ float tile[64][65];
  int bx = blockIdx.x;
  const float* S; __hip_bfloat16* D; int K, N, n0, k0;
  if (bx < 576) { S = w_fc;   D = wfcT;   K = DD; N = FF; n0 = (bx % 48) * 64; k0 = (bx / 48) * 64; }
  else { bx -= 576; S = w_proj; D = wprojT; K = FF; N = DD; n0 = (bx % 12) * 64; k0 = (bx / 12) * 64; }
  S += (size_t)blockIdx.z * K * N;
  D += (size_t)blockIdx.z * K * N;
  int tid = threadIdx.x;
#pragma unroll
  for (int i = 0; i < 4; ++i) {
    int slot = i * 256 + tid;
    int r = slot >> 4, c4 = slot & 15;
    float4 v = *(const float4*)&S[(size_t)(k0 + r) * N + n0 + c4 * 4];
    tile[r][c4 * 4 + 0] = v.x; tile[r][c4 * 4 + 1] = v.y;
    tile[r][c4 * 4 + 2] = v.z; tile[r][c4 * 4 + 3] = v.w;
  }
  __syncthreads();
#pragma unroll
  for (int i = 0; i < 4; ++i) {
    int slot = i * 256 + tid;
    int n = slot >> 4, kc = slot & 15;
    union { ushort4 u; __hip_bfloat16 h[4]; } cv;
    cv.h[0] = __float2bfloat16(tile[kc * 4 + 0][n]);
    cv.h[1] = __float2bfloat16(tile[kc * 4 + 1][n]);
    cv.h[2] = __float2bfloat16(tile[kc * 4 + 2][n]);
    cv.h[3] = __float2bfloat16(tile[kc * 4 + 3][n]);
    *(ushort4*)&D[(size_t)(n0 + n) * K + k0 + kc * 4] = cv.u;
  }
}

// fast exact-gelu via A&S 7.1.26 erf (max abs err 1.5e-7)
__device__ __forceinline__ float gelu_f(float v) {
  float z = v * 0.70710678118654752f;
  float az = fabsf(z);
  float t = 1.0f / (1.0f + 0.3275911f * az);
  float poly = t * (0.254829592f + t * (-0.284496736f + t * (1.421413741f +
               t * (-1.453152027f + t * 1.061405429f))));
  float erf_abs = 1.0f - poly * __expf(-az * az);
  float erf = copysignf(erf_abs, z);
  return 0.5f * v * (1.0f + erf);
}

// chunk swizzle for BK=32 rows (4 x 16B chunks/row)
__device__ __forceinline__ int swz4(int m) { return (m + (m >> 2)) & 3; }

// GEMM1: H = gelu(Xg @ wfcT + b_fc); 128x128 tile, BK=32, 2-buf pipelined K-loop.
__global__ __launch_bounds__(256) void gemm1_kernel(const __hip_bfloat16* __restrict__ Xg,
    const __hip_bfloat16* __restrict__ wfcT, const float* __restrict__ b_fc,
    __hip_bfloat16* __restrict__ H, const int* __restrict__ offs,
    const int* __restrict__ tile1, const int* __restrict__ meta) {
  __shared__ __align__(16) short As[2][128 * 32];
  __shared__ __align__(16) short Bs[2][128 * 32];
  if ((int)blockIdx.y >= meta[0]) return;
  int tv = tile1[blockIdx.y];
  int e = tv >> 20;
  int m_base = tv & 0xFFFFF;
  int off_e = offs[e];
  int n_e = offs[e + 1] - off_e;
  int n0 = blockIdx.x * 128;
  const short* A = (const short*)Xg + (size_t)(off_e + m_base) * DD;
  const short* B = (const short*)wfcT + (size_t)e * FF * DD + (size_t)n0 * DD;
  int tid = threadIdx.x;
  int lane = tid & 63, wid = tid >> 6;
  int l15 = lane & 15, q = lane >> 4;
  int wm = wid & 1, wn = wid >> 1;
  int fs0 = tid, fs1 = tid + 256;
  int m0 = fs0 >> 2, c0 = (fs0 & 3) ^ swz4(m0);
  int m1 = fs1 >> 2, c1 = (fs1 & 3) ^ swz4(m1);
  const short* gA0 = A + (size_t)m0 * DD + c0 * 8;
  const short* gA1 = A + (size_t)m1 * DD + c1 * 8;
  const short* gB0 = B + (size_t)m0 * DD + c0 * 8;
  const short* gB1 = B + (size_t)m1 * DD + c1 * 8;
  int aoff[4], boff[4];
#pragma unroll
  for (int mi = 0; mi < 4; ++mi) {
    int r = wm * 64 + mi * 16 + l15;
    aoff[mi] = (r * 4 + (q ^ swz4(r))) * 8;
  }
#pragma unroll
  for (int ni = 0; ni < 4; ++ni) {
    int r = wn * 64 + ni * 16 + l15;
    boff[ni] = (r * 4 + (q ^ swz4(r))) * 8;
  }
  f32x4 acc[4][4] = {};
  __builtin_amdgcn_global_load_lds((gas1_t)gA0, (las3_t)(&As[0][0] + fs0 * 8), 16, 0, 0);
  __builtin_amdgcn_global_load_lds((gas1_t)gA1, (las3_t)(&As[0][0] + fs1 * 8), 16, 0, 0);
  __builtin_amdgcn_global_load_lds((gas1_t)gB0, (las3_t)(&Bs[0][0] + fs0 * 8), 16, 0, 0);
  __builtin_amdgcn_global_load_lds((gas1_t)gB1, (las3_t)(&Bs[0][0] + fs1 * 8), 16, 0, 0);
  gA0 += 32; gA1 += 32; gB0 += 32; gB1 += 32;
  for (int it = 0; it < DD / 32; ++it) {
    int cur = it & 1, nxt = cur ^ 1;
    short* curA = &As[cur][0];
    short* curB = &Bs[cur][0];
    __builtin_amdgcn_s_barrier();
    __builtin_amdgcn_global_load_lds((gas1_t)gA0, (las3_t)(&As[nxt][0] + fs0 * 8), 16, 0, 0);
    __builtin_amdgcn_global_load_lds((gas1_t)gA1, (las3_t)(&As[nxt][0] + fs1 * 8), 16, 0, 0);
    __builtin_amdgcn_global_load_lds((gas1_t)gB0, (las3_t)(&Bs[nxt][0] + fs0 * 8), 16, 0, 0);
    __builtin_amdgcn_global_load_lds((gas1_t)gB1, (las3_t)(&Bs[nxt][0] + fs1 * 8), 16, 0, 0);
    gA0 += 32; gA1 += 32; gB0 += 32; gB1 += 32;
    __builtin_amdgcn_s_waitcnt(WAITCNT_VM4);
    __builtin_amdgcn_s_barrier();
    bf16x8 af[4], bfr[4];
#pragma unroll
    for (int mi = 0; mi < 4; ++mi) af[mi] = *(const bf16x8*)(curA + aoff[mi]);
#pragma unroll
    for (int ni = 0; ni < 4; ++ni) bfr[ni] = *(const bf16x8*)(curB + boff[ni]);
#pragma unroll
    for (int mi = 0; mi < 4; ++mi)
#pragma unroll
      for (int ni = 0; ni < 4; ++ni)
        acc[mi][ni] = __builtin_amdgcn_mfma_f32_16x16x32_bf16(af[mi], bfr[ni], acc[mi][ni], 0, 0, 0);
  }
  float bias[4];
#pragma unroll
  for (int ni = 0; ni < 4; ++ni) bias[ni] = b_fc[e * FF + n0 + wn * 64 + ni * 16 + l15];
  __hip_bfloat16* Hp = H + (size_t)(off_e + m_base) * FF + n0;
#pragma unroll
  for (int mi = 0; mi < 4; ++mi) {
#pragma unroll
    for (int r = 0; r < 4; ++r) {
      int ml = wm * 64 + mi * 16 + q * 4 + r;
      if (m_base + ml < n_e) {
#pragma unroll
        for (int ni = 0; ni < 4; ++ni) {
          int nl = wn * 64 + ni * 16 + l15;
          float v = acc[mi][ni][r] + bias[ni];
          Hp[(size_t)ml * FF + nl] = __float2bfloat16(gelu_f(v));
        }
      }
    }
  }
}

// GEMM2: out[tok] += w(slot)*(H[slot] @ wprojT + b_proj); 64x384 tile, BK=32,
// pipelined; fused combine via fp32 atomics (weights sum to 1 -> bias exact).
__global__ __launch_bounds__(256) void gemm2_kernel(const __hip_bfloat16* __restrict__ H,
    const __hip_bfloat16* __restrict__ wprojT, const float* __restrict__ b_proj,
    const float* __restrict__ slotW, const int* __restrict__ slotTok,
    float* __restrict__ out, const int* __restrict__ offs,
    const int* __restrict__ tile2, const int* __restrict__ meta) {
  __shared__ __align__(16) short As[2][64 * 32];
  __shared__ __align__(16) short Bs[2][384 * 32];
  if ((int)blockIdx.y >= meta[1]) return;
  int tv = tile2[blockIdx.y];
  int e = tv >> 20;
  int m_base = tv & 0xFFFFF;
  int off_e = offs[e];
  int n_e = offs[e + 1] - off_e;
  int n0 = blockIdx.x * 384;
  const short* A = (const short*)H + (size_t)(off_e + m_base) * FF;
  const short* B = (const short*)wprojT + (size_t)e * DD * FF + (size_t)n0 * FF;
  int tid = threadIdx.x;
  int lane = tid & 63, wid = tid >> 6;   // wave wid covers N-strip [wid*96, wid*96+96)
  int l15 = lane & 15, q = lane >> 4;
  // staging: A = 256 chunks (1 instr), B = 1536 chunks (6 instrs)
  int mA = tid >> 2, cA = (tid & 3) ^ swz4(mA);
  const short* gA = A + (size_t)mA * FF + cA * 8;
  const short* gB[6];
  int fsB[6];
#pragma unroll
  for (int i = 0; i < 6; ++i) {
    int fs = tid + i * 256;
    int m = fs >> 2, c = (fs & 3) ^ swz4(m);
    fsB[i] = fs;
    gB[i] = B + (size_t)m * FF + c * 8;
  }
  int aoff[4], boff[6];
#pragma unroll
  for (int mi = 0; mi < 4; ++mi) {
    int r = mi * 16 + l15;
    aoff[mi] = (r * 4 + (q ^ swz4(r))) * 8;
  }
#pragma unroll
  for (int ni = 0; ni < 6; ++ni) {
    int r = wid * 96 + ni * 16 + l15;
    boff[ni] = (r * 4 + (q ^ swz4(r))) * 8;
  }
  f32x4 acc[4][6] = {};
  __builtin_amdgcn_global_load_lds((gas1_t)gA, (las3_t)(&As[0][0] + tid * 8), 16, 0, 0);
#pragma unroll
  for (int i = 0; i < 6; ++i)
    __builtin_amdgcn_global_load_lds((gas1_t)gB[i], (las3_t)(&Bs[0][0] + fsB[i] * 8), 16, 0, 0);
  gA += 32;
#pragma unroll
  for (int i = 0; i < 6; ++i) gB[i] += 32;
  for (int it = 0; it < FF / 32; ++it) {
    int cur = it & 1, nxt = cur ^ 1;
    short* curA = &As[cur][0];
    short* curB = &Bs[cur][0];
    __builtin_amdgcn_s_barrier();
    __builtin_amdgcn_global_load_lds((gas1_t)gA, (las3_t)(&As[nxt][0] + tid * 8), 16, 0, 0);
#pragma unroll
    for (int i = 0; i < 6; ++i)
      __builtin_amdgcn_global_load_lds((gas1_t)gB[i], (las3_t)(&Bs[nxt][0] + fsB[i] * 8), 16, 0, 0);
    gA += 32;
#pragma unroll
    for (int i = 0; i < 6; ++i) gB[i] += 32;
    __builtin_amdgcn_s_waitcnt(WAITCNT_VM7);
    __builtin_amdgcn_s_barrier();
    bf16x8 af[4], bfr[6];
#pragma unroll
    for (int mi = 0; mi < 4; ++mi) af[mi] = *(const bf16x8*)(curA + aoff[mi]);
#pragma unroll
    for (int ni = 0; ni < 6; ++ni) bfr[ni] = *(const bf16x8*)(curB + boff[ni]);
#pragma unroll
    for (int mi = 0; mi < 4; ++mi)
#pragma unroll
      for (int ni = 0; ni < 6; ++ni)
        acc[mi][ni] = __builtin_amdgcn_mfma_f32_16x16x32_bf16(af[mi], bfr[ni], acc[mi][ni], 0, 0, 0);
  }
  float bias[6];
#pragma unroll
  for (int ni = 0; ni < 6; ++ni) bias[ni] = b_proj[e * DD + n0 + wid * 96 + ni * 16 + l15];
#pragma unroll
  for (int mi = 0; mi < 4; ++mi) {
#pragma unroll
    for (int r = 0; r < 4; ++r) {
      int ml = mi * 16 + q * 4 + r;
      if (m_base + ml < n_e) {
        int slot = off_e + m_base + ml;
        float w = slotW[slot];
        int tok = slotTok[slot];
        float* op = out + (size_t)tok * DD + n0 + wid * 96;
#pragma unroll
        for (int ni = 0; ni < 6; ++ni)
          atomicAdd(&op[ni * 16 + l15], w * (acc[mi][ni][r] + bias[ni]));
      }
    }
  }
}

extern "C" void kernel_launch(void* const* d_in, const int* in_sizes, int n_in,
                              void* d_out, int out_size, void* d_ws, size_t ws_size,
                              hipStream_t stream) {
  const float* x        = (const float*)d_in[0];
  const float* router_w = (const float*)d_in[1];
  const float* w_fc     = (const float*)d_in[2];
  const float* b_fc     = (const float*)d_in[3];
  const float* w_proj   = (const float*)d_in[4];
  const float* b_proj   = (const float*)d_in[5];
  float* out = (float*)d_out;

  char* p = (char*)d_ws;
  auto alloc = [&](size_t bytes) {
    char* r = p;
    p += (bytes + 255) & ~(size_t)255;
    return r;
  };
  __hip_bfloat16* wfcT   = (__hip_bfloat16*)alloc((size_t)EE * FF * DD * 2);  // [E][F][D]
  __hip_bfloat16* wprojT = (__hip_bfloat16*)alloc((size_t)EE * DD * FF * 2);  // [E][D][F]
  __hip_bfloat16* Xg     = (__hip_bfloat16*)alloc((size_t)NSLOT_PAD * DD * 2);
  __hip_bfloat16* H      = (__hip_bfloat16*)alloc((size_t)NSLOT_PAD * FF * 2);
  int*   tokE    = (int*)alloc(TT * 2 * 4);
  float* tokW    = (float*)alloc(TT * 2 * 4);
  int*   slotIdx = (int*)alloc(TT * 2 * 4);
  float* slotW   = (float*)alloc(NSLOT_PAD * 4);
  int*   slotTok = (int*)alloc(NSLOT_PAD * 4);
  int*   blkCnt  = (int*)alloc(256 * EE * 4);
  int*   blkBase = (int*)alloc(256 * EE * 4);
  int*   tile1   = (int*)alloc(128 * 4);
  int*   tile2   = (int*)alloc(256 * 4);
  int*   offs    = (int*)alloc(64);
  int*   meta    = (int*)alloc(64);

  hipMemsetAsync(out, 0, (size_t)out_size * 4, stream);
  router2_kernel<<<256, 256, 0, stream>>>(x, router_w, tokE, tokW, blkCnt);
  offsets2_kernel<<<1, 256, 0, stream>>>(blkCnt, offs, blkBase, tile1, tile2, meta);
  scatter_gather2_kernel<<<256, 256, 0, stream>>>(x, tokE, tokW, blkBase, slotIdx, slotW, slotTok, Xg);
  transpose_convert_kernel<<<dim3(1152, 1, EE), 256, 0, stream>>>(w_fc, wfcT, w_proj, wprojT);
  gemm1_kernel<<<dim3(FF / 128, 72), 256, 0, stream>>>(Xg, wfcT, b_fc, H, offs, tile1, meta);
  gemm2_kernel<<<dim3(DD / 384, 136), 256, 0, stream>>>(H, wprojT, b_proj, slotW, slotTok, out, offs, tile2, meta);
}